// Round 11
// baseline (81.681 us; speedup 1.0000x reference)
//
#include <hip/hip_runtime.h>
#include <math.h>

#define NN 50000
#define FD 128
#define HDIM 256
#define NE 800000
#define NBR_CAP 512
#define M_CAP 8192
#define TT 7
#define TPB 256
#define GB 32              // k_graph / k_step blocks
#define PSLICE 36          // 32 blocks x 36 = 1152 p-values
#define ECHUNK 2048

// ws offsets
#define O_NBRCNT   0       // zeroed by 64-B memset node
#define O_MCNT     64
#define O_GACC     128     // 1024 f -> 4224
#define O_DEG      4224    // NN f -> 204224
#define O_BITMAP   204224  // 1568 u32 -> 210496
#define O_ZERO_END 210496  // k_nbr zeroes [64, 210496)
#define O_NBRNODE  210496  // NBR_CAP i
#define O_NBRW     212544  // NBR_CAP f
#define O_MS       214592  // M_CAP i
#define O_MD       247360  // M_CAP i
#define O_MW       280128  // M_CAP f -> 312896
#define O_HBUF     312896  // (TT+1)*HDIM f = 8192 -> 321088
#define O_CBUF     321088  // (TT+1)*HDIM f = 8192 -> 329280

__device__ __forceinline__ float sigm(float v) { return 1.f / (1.f + expf(-v)); }
__device__ __forceinline__ float dis_of(float dg) {
    return dg > 0.f ? rsqrtf(fmaxf(dg, 1e-20f)) : 0.f;
}

// Scan 1: zero ctrl/deg/bitmap/gacc; collect nbr(0); warm theta+w_hh into L3.
__global__ void k_nbr(const int* __restrict__ ei, const float* __restrict__ ew,
                      const float* __restrict__ theta_x, const float* __restrict__ theta_h,
                      const float* __restrict__ w_hh, char* __restrict__ ws) {
    int*      nbrCnt = (int*)(ws + O_NBRCNT);
    int*      nbrNode= (int*)(ws + O_NBRNODE);
    float*    nbrW   = (float*)(ws + O_NBRW);

    int gid = blockIdx.x * blockDim.x + threadIdx.x;
    if (gid < (O_ZERO_END - O_MCNT) / 4) ((unsigned*)(ws + O_MCNT))[gid] = 0u;

    // L3 warm: blocks 600+ stream theta_x|theta_h|w_hh (5.75 MB) into a sink.
    if (blockIdx.x >= 600) {
        const int wb = blockIdx.x - 600, NWB = 182;
        const float4* tx4 = (const float4*)theta_x;   //  98304 f4
        const float4* th4 = (const float4*)theta_h;   // 196608 f4
        const float4* wh4 = (const float4*)w_hh;      //  65536 f4
        float acc = 0.f;
        for (int idx = wb * 256 + threadIdx.x; idx < 360448; idx += NWB * 256) {
            float4 v;
            if (idx < 98304)       v = tx4[idx];
            else if (idx < 294912) v = th4[idx - 98304];
            else                   v = wh4[idx - 294912];
            acc += v.x + v.y + v.z + v.w;
        }
        asm volatile("" :: "v"(acc));
    }

    int e0 = gid * 4;
    if (e0 >= NE) return;
    int4 d4 = *(const int4*)&ei[NE + e0];
    float4 w4 = *(const float4*)&ew[e0];
    int dd[4] = {d4.x, d4.y, d4.z, d4.w};
    float wv[4] = {w4.x, w4.y, w4.z, w4.w};
    #pragma unroll
    for (int k = 0; k < 4; ++k) {
        if (dd[k] == 0 && wv[k] != 0.f) {
            int s = ei[e0 + k];
            if (s != 0) {
                int slot = atomicAdd(nbrCnt, 1);
                if (slot < NBR_CAP) { nbrNode[slot] = s; nbrW[slot] = wv[k]; }
            }
        }
    }
}

// Scan 2: match edges with d==0 or d in nbr(0); record (s,d,w); mark needed nodes.
__global__ void k_match(const int* __restrict__ ei, const float* __restrict__ ew,
                        char* __restrict__ ws) {
    const int* nbrCnt = (const int*)(ws + O_NBRCNT);
    const int* nbrNode= (const int*)(ws + O_NBRNODE);
    int*      mCnt   = (int*)(ws + O_MCNT);
    int*      mS     = (int*)(ws + O_MS);
    int*      mD     = (int*)(ws + O_MD);
    float*    mW     = (float*)(ws + O_MW);
    unsigned* bitmap = (unsigned*)(ws + O_BITMAP);

    __shared__ int sNode[NBR_CAP];
    __shared__ int sCnt;
    if (threadIdx.x == 0) sCnt = min(*nbrCnt, NBR_CAP);
    __syncthreads();
    int cnt = sCnt;
    for (int i = threadIdx.x; i < cnt; i += blockDim.x) sNode[i] = nbrNode[i];
    __syncthreads();
    if (blockIdx.x == 0 && threadIdx.x == 0) atomicOr(&bitmap[0], 1u);

    int i = blockIdx.x * blockDim.x + threadIdx.x;
    int e0 = i * 4;
    if (e0 >= NE) return;
    int4 s4 = *(const int4*)&ei[e0];
    int4 d4 = *(const int4*)&ei[NE + e0];
    float4 w4 = *(const float4*)&ew[e0];
    int ss[4] = {s4.x, s4.y, s4.z, s4.w};
    int dd[4] = {d4.x, d4.y, d4.z, d4.w};
    float wv[4] = {w4.x, w4.y, w4.z, w4.w};
    bool m[4];
    #pragma unroll
    for (int k = 0; k < 4; ++k) m[k] = (dd[k] == 0);
    for (int j = 0; j < cnt; ++j) {
        int nv = sNode[j];
        #pragma unroll
        for (int k = 0; k < 4; ++k) m[k] |= (dd[k] == nv);
    }
    #pragma unroll
    for (int k = 0; k < 4; ++k) {
        int s = ss[k], d = dd[k];
        float w = wv[k];
        if (s == d || w == 0.f || !m[k]) continue;
        int slot = atomicAdd(mCnt, 1);
        if (slot < M_CAP) { mS[slot] = s; mD[slot] = d; mW[slot] = w; }
        atomicOr(&bitmap[s >> 5], 1u << (s & 31));
        atomicOr(&bitmap[d >> 5], 1u << (d & 31));
    }
}

// Scan 3: deg[s] += w only for bitmap-marked srcs.
__global__ void k_deg(const int* __restrict__ ei, const float* __restrict__ ew,
                      char* __restrict__ ws) {
    const unsigned* bitmap = (const unsigned*)(ws + O_BITMAP);
    float* deg = (float*)(ws + O_DEG);
    int i = blockIdx.x * blockDim.x + threadIdx.x;
    int e0 = i * 4;
    if (e0 >= NE) return;
    int4 s4 = *(const int4*)&ei[e0];
    int4 d4 = *(const int4*)&ei[NE + e0];
    float4 w4 = *(const float4*)&ew[e0];
    int ss[4] = {s4.x, s4.y, s4.z, s4.w};
    int dd[4] = {d4.x, d4.y, d4.z, d4.w};
    float wv[4] = {w4.x, w4.y, w4.z, w4.w};
    #pragma unroll
    for (int k = 0; k < 4; ++k) {
        int s = ss[k];
        if (s == dd[k] || wv[k] == 0.f) continue;
        if (bitmap[s >> 5] & (1u << (s & 31)))
            atomicAdd(&deg[s], wv[k]);
    }
}

// Graph: block-local T-slice (36 p) + gemv into gacc. 32 blocks x 256 threads.
__global__ __launch_bounds__(TPB) void k_graph(
    const float* __restrict__ x, const float* __restrict__ h,
    const float* __restrict__ theta_x, const float* __restrict__ theta_h,
    char* __restrict__ ws) {

    const float* deg    = (const float*)(ws + O_DEG);
    const int*   nbrCnt = (const int*)(ws + O_NBRCNT);
    const int*   mCnt   = (const int*)(ws + O_MCNT);
    float*       gacc   = (float*)(ws + O_GACC);
    const int*   nbrNode= (const int*)(ws + O_NBRNODE);
    const float* nbrW   = (const float*)(ws + O_NBRW);
    const int*   mS     = (const int*)(ws + O_MS);
    const int*   mD     = (const int*)(ws + O_MD);
    const float* mW     = (const float*)(ws + O_MW);

    __shared__ int   sNode[NBR_CAP];
    __shared__ float sWl[NBR_CAP];
    __shared__ float cf1[ECHUNK], cf2[ECHUNK];
    __shared__ int   sS[ECHUNK];
    __shared__ float tp1[7][PSLICE], tp2[7][PSLICE];
    __shared__ float tslice[PSLICE];
    __shared__ int   sCnt, sMcnt;

    const int tid = threadIdx.x, bid = blockIdx.x;

    if (tid == 0) { sCnt = min(*nbrCnt, NBR_CAP); sMcnt = min(*mCnt, M_CAP); }
    __syncthreads();
    const int ncnt = sCnt, mcnt = sMcnt;
    for (int i = tid; i < ncnt; i += TPB) { sNode[i] = nbrNode[i]; sWl[i] = nbrW[i]; }
    __syncthreads();

    // ---- phase A: block-local T-slice ----
    const float dis0 = dis_of(deg[0]);
    const int pl = tid % PSLICE, gr = tid / PSLICE;       // 7 full edge-groups
    const int p = bid * PSLICE + pl;
    const bool isx = p < 3 * FD;
    const int q = isx ? p : p - 3 * FD;
    const int korder = isx ? (q / FD) : (q / HDIM);
    const int f = isx ? (q % FD) : (q % HDIM);
    const float* fbase = isx ? (x + f) : (h + f);
    const int fstride = isx ? FD : HDIM;
    const float f0 = fbase[0];

    float a1 = 0.f, a2 = 0.f;
    for (int c0i = 0; c0i < mcnt; c0i += ECHUNK) {
        int clen = min(ECHUNK, mcnt - c0i);
        for (int i = tid; i < clen; i += TPB) {           // per-edge coefs
            int sI = mS[c0i + i], dI = mD[c0i + i];
            float w = mW[c0i + i];
            float disd = dis_of(deg[dI]);
            float wn = dis_of(deg[sI]) * w * disd;
            float Wd = 0.f;
            for (int j = 0; j < ncnt; ++j) Wd += (sNode[j] == dI) ? sWl[j] : 0.f;
            cf1[i] = (dI == 0) ? wn : 0.f;
            cf2[i] = wn * (dis0 * disd * Wd);
            sS[i] = sI;
        }
        __syncthreads();
        if (gr < 7) {
            for (int i = gr; i < clen; i += 7) {          // gather-reduce
                float v = fbase[(size_t)sS[i] * fstride];
                a1 += cf1[i] * v;
                a2 += cf2[i] * v;
            }
        }
        __syncthreads();
    }
    if (gr < 7) { tp1[gr][pl] = a1; tp2[gr][pl] = a2; }
    __syncthreads();
    if (tid < PSLICE) {
        float A1 = 0.f, A2 = 0.f;
        #pragma unroll
        for (int g2 = 0; g2 < 7; ++g2) { A1 += tp1[g2][tid]; A2 += tp2[g2][tid]; }
        tslice[tid] = (korder == 0) ? f0 : ((korder == 1) ? -A1 : 2.f * A2 - f0);
    }
    __syncthreads();

    // ---- phase B: gemv over this block's 36 p-rows ----
    {
        const int oq = tid & 63, pseg = tid >> 6;
        const int p0 = bid * PSLICE + pseg * 9;
        float4 a0 = {0,0,0,0}, b1 = {0,0,0,0}, a2v = {0,0,0,0}, a3 = {0,0,0,0};
        #pragma unroll
        for (int pp = 0; pp < 9; ++pp) {
            int p2 = p0 + pp;
            bool ix = p2 < 3 * FD;
            int qq = ix ? p2 : p2 - 3 * FD;
            float tv = tslice[pseg * 9 + pp];
            const float* bb = ix ? (theta_x + (size_t)qq * HDIM)
                                 : (theta_h + (size_t)qq * HDIM);
            size_t gs = ix ? (size_t)(3 * FD) * HDIM : (size_t)(3 * HDIM) * HDIM;
            float4 v0 = *(const float4*)&bb[oq * 4];
            float4 v1 = *(const float4*)&bb[gs + oq * 4];
            float4 v2 = *(const float4*)&bb[2 * gs + oq * 4];
            float4 v3 = *(const float4*)&bb[3 * gs + oq * 4];
            a0.x += tv * v0.x; a0.y += tv * v0.y; a0.z += tv * v0.z; a0.w += tv * v0.w;
            b1.x += tv * v1.x; b1.y += tv * v1.y; b1.z += tv * v1.z; b1.w += tv * v1.w;
            a2v.x += tv * v2.x; a2v.y += tv * v2.y; a2v.z += tv * v2.z; a2v.w += tv * v2.w;
            a3.x += tv * v3.x; a3.y += tv * v3.y; a3.z += tv * v3.z; a3.w += tv * v3.w;
        }
        int ob = oq * 4;
        atomicAdd(&gacc[0 * HDIM + ob + 0], a0.x); atomicAdd(&gacc[0 * HDIM + ob + 1], a0.y);
        atomicAdd(&gacc[0 * HDIM + ob + 2], a0.z); atomicAdd(&gacc[0 * HDIM + ob + 3], a0.w);
        atomicAdd(&gacc[1 * HDIM + ob + 0], b1.x); atomicAdd(&gacc[1 * HDIM + ob + 1], b1.y);
        atomicAdd(&gacc[1 * HDIM + ob + 2], b1.z); atomicAdd(&gacc[1 * HDIM + ob + 3], b1.w);
        atomicAdd(&gacc[2 * HDIM + ob + 0], a2v.x); atomicAdd(&gacc[2 * HDIM + ob + 1], a2v.y);
        atomicAdd(&gacc[2 * HDIM + ob + 2], a2v.z); atomicAdd(&gacc[2 * HDIM + ob + 3], a2v.w);
        atomicAdd(&gacc[3 * HDIM + ob + 0], a3.x); atomicAdd(&gacc[3 * HDIM + ob + 1], a3.y);
        atomicAdd(&gacc[3 * HDIM + ob + 2], a3.z); atomicAdd(&gacc[3 * HDIM + ob + 3], a3.w);
    }
}

// Gates: 1 block, 256 threads. gacc -> h0, c0 (slot 0 of hbuf/cbuf).
__global__ void k_gates(const float* __restrict__ c,
                        const float* __restrict__ bias_x, const float* __restrict__ bias_h,
                        const float* __restrict__ w_c, const float* __restrict__ b_gate,
                        char* __restrict__ ws) {
    const float* gacc = (const float*)(ws + O_GACC);
    float* hbuf = (float*)(ws + O_HBUF);
    float* cbuf = (float*)(ws + O_CBUF);
    const int o = threadIdx.x;
    float g0 = gacc[0 * HDIM + o] + bias_x[0 * HDIM + o] + bias_h[0 * HDIM + o];
    float g1 = gacc[1 * HDIM + o] + bias_x[1 * HDIM + o] + bias_h[1 * HDIM + o];
    float g2 = gacc[2 * HDIM + o] + bias_x[2 * HDIM + o] + bias_h[2 * HDIM + o];
    float g3 = gacc[3 * HDIM + o] + bias_x[3 * HDIM + o] + bias_h[3 * HDIM + o];
    float c0 = c[o];
    float I  = sigm(g0 + w_c[0 * HDIM + o] * c0 + b_gate[0 * HDIM + o]);
    float Fg = sigm(g1 + w_c[1 * HDIM + o] * c0 + b_gate[1 * HDIM + o]);
    float Cn = Fg * c0 + I * tanhf(g2 + b_gate[2 * HDIM + o]);
    float O  = sigm(g3 + w_c[2 * HDIM + o] * Cn + b_gate[3 * HDIM + o]);
    hbuf[o] = O * tanhf(Cn);
    cbuf[o] = Cn;
}

// One LSTM step (t from kernel arg). 32 blocks x 256 threads, pure dataflow:
// reads hbuf/cbuf slot t, writes slot t+1; block b owns dims [b*8, b*8+8).
// sinp (= out[t-1] for t>=1) computed redundantly per block; block 0 stores it.
__global__ __launch_bounds__(TPB) void k_step(
    int t, const float* __restrict__ x,
    const float* __restrict__ w_ih, const float* __restrict__ w_hh,
    const float* __restrict__ b_ih, const float* __restrict__ b_hh,
    const float* __restrict__ w_out, const float* __restrict__ b_out,
    float* __restrict__ out, char* __restrict__ ws) {

    float* hbuf = (float*)(ws + O_HBUF);
    float* cbuf = (float*)(ws + O_CBUF);

    __shared__ __align__(16) float sh[HDIM];
    __shared__ float sdot[32];
    __shared__ float swsum[4];

    const int tid = threadIdx.x, bid = blockIdx.x;
    const float* hr = hbuf + t * HDIM;

    // full h(t) -> LDS (coalesced), plus per-thread w_out product for sinp
    float hv = hr[tid];
    sh[tid] = hv;
    float pw = hv * w_out[tid];
    pw += __shfl_down(pw, 32);
    pw += __shfl_down(pw, 16);
    pw += __shfl_down(pw, 8);
    pw += __shfl_down(pw, 4);
    pw += __shfl_down(pw, 2);
    pw += __shfl_down(pw, 1);
    if ((tid & 63) == 0) swsum[tid >> 6] = pw;
    __syncthreads();
    const float bo = b_out[0];
    const float sval = swsum[0] + swsum[1] + swsum[2] + swsum[3] + bo; // = out[t-1]
    const float sinp = (t == 0) ? x[FD - 1] : sval;
    if (t > 0 && bid == 0 && tid == 0) out[t - 1] = sval;

    // dot: 32 rows/block, 8 lanes/row x 32 FMA
    const int rl = tid >> 3, seg = tid & 7;
    const int grow = (rl >> 3) * HDIM + bid * 8 + (rl & 7);
    const float* wrow = w_hh + (size_t)grow * HDIM + seg * 32;
    const float* shh = &sh[seg * 32];
    float acc = 0.f;
    #pragma unroll
    for (int k = 0; k < 8; ++k) {
        float4 wv = *(const float4*)&wrow[k * 4];
        float4 hv4 = *(const float4*)&shh[k * 4];
        acc += hv4.x * wv.x + hv4.y * wv.y + hv4.z * wv.z + hv4.w * wv.w;
    }
    acc += __shfl_down(acc, 4);
    acc += __shfl_down(acc, 2);
    acc += __shfl_down(acc, 1);
    if (seg == 0) sdot[rl] = acc + sinp * w_ih[grow] + b_ih[grow] + b_hh[grow];
    __syncthreads();

    if (tid < 8) {
        const int dim = bid * 8 + tid;
        float cd = cbuf[t * HDIM + dim];
        float iv = sdot[tid], fv = sdot[8 + tid], gv = sdot[16 + tid], ov = sdot[24 + tid];
        float cn = sigm(fv) * cd + sigm(iv) * tanhf(gv);
        float hn = sigm(ov) * tanhf(cn);
        hbuf[(t + 1) * HDIM + dim] = hn;
        cbuf[(t + 1) * HDIM + dim] = cn;
    }
}

// Final: out[TT-1] from hbuf slot TT.
__global__ void k_fin(const float* __restrict__ w_out, const float* __restrict__ b_out,
                      float* __restrict__ out, char* __restrict__ ws) {
    const float* hr = (const float*)(ws + O_HBUF) + TT * HDIM;
    const int tid = threadIdx.x;            // 64 lanes
    float pw = 0.f;
    #pragma unroll
    for (int j = 0; j < 4; ++j) pw += hr[tid * 4 + j] * w_out[tid * 4 + j];
    pw += __shfl_down(pw, 32);
    pw += __shfl_down(pw, 16);
    pw += __shfl_down(pw, 8);
    pw += __shfl_down(pw, 4);
    pw += __shfl_down(pw, 2);
    pw += __shfl_down(pw, 1);
    if (tid == 0) out[TT - 1] = pw + b_out[0];
}

extern "C" void kernel_launch(void* const* d_in, const int* in_sizes, int n_in,
                              void* d_out, int out_size, void* d_ws, size_t ws_size,
                              hipStream_t stream) {
    const float* x       = (const float*)d_in[0];
    const int*   ei      = (const int*)d_in[1];
    const float* ew      = (const float*)d_in[2];
    const float* h       = (const float*)d_in[3];
    const float* c       = (const float*)d_in[4];
    const float* theta_x = (const float*)d_in[5];
    const float* bias_x  = (const float*)d_in[6];
    const float* theta_h = (const float*)d_in[7];
    const float* bias_h  = (const float*)d_in[8];
    const float* w_c     = (const float*)d_in[9];
    const float* b_gate  = (const float*)d_in[10];
    const float* w_ih    = (const float*)d_in[11];
    const float* w_hh    = (const float*)d_in[12];
    const float* b_ih    = (const float*)d_in[13];
    const float* b_hh    = (const float*)d_in[14];
    const float* w_out   = (const float*)d_in[15];
    const float* b_out   = (const float*)d_in[16];
    char* ws = (char*)d_ws;
    float* out = (float*)d_out;

    hipMemsetAsync(ws, 0, 64, stream);          // nbrCnt; rest zeroed by k_nbr

    int eb4 = (NE / 4 + TPB - 1) / TPB;         // 782 blocks
    k_nbr<<<eb4, TPB, 0, stream>>>(ei, ew, theta_x, theta_h, w_hh, ws);
    k_match<<<eb4, TPB, 0, stream>>>(ei, ew, ws);
    k_deg<<<eb4, TPB, 0, stream>>>(ei, ew, ws);
    k_graph<<<GB, TPB, 0, stream>>>(x, h, theta_x, theta_h, ws);
    k_gates<<<1, TPB, 0, stream>>>(c, bias_x, bias_h, w_c, b_gate, ws);
    for (int t = 0; t < TT; ++t)
        k_step<<<GB, TPB, 0, stream>>>(t, x, w_ih, w_hh, b_ih, b_hh, w_out, b_out, out, ws);
    k_fin<<<1, 64, 0, stream>>>(w_out, b_out, out, ws);
}

// Round 12
// 73.565 us; speedup vs baseline: 1.1103x; 1.1103x over previous
//
#include <hip/hip_runtime.h>
#include <math.h>

#define NN 50000
#define FD 128
#define HDIM 256
#define NE 800000
#define NBR_CAP 512
#define M_CAP 8192
#define TT 7
#define TPB 256
#define GB 48              // k_graph blocks
#define PSLICE 24          // 48 x 24 = 1152 p-values
#define GRP 10             // gather groups per block (256/24)
#define ECHUNK 2048
#define SB 32              // k_step blocks

// ws offsets
#define O_NBRCNT   0       // zeroed by 64-B memset node
#define O_MCNT     64
#define O_DEG      128     // NN f -> 200128
#define O_BITMAP   200128  // 1568 u32 -> 206400
#define O_ZERO_END 206400  // k_nbr zeroes [64, 206400)
#define O_NBRNODE  206400  // NBR_CAP i
#define O_NBRW     208448  // NBR_CAP f
#define O_MS       210496  // M_CAP i
#define O_MD       243264  // M_CAP i
#define O_MW       276032  // M_CAP f -> 308800
#define O_GPART    308800  // GB*1024 f = 196608 -> 505408 (fully overwritten, no zero)
#define O_HBUF     505408  // (TT+1)*HDIM f -> 513600
#define O_CBUF     513600  // (TT+1)*HDIM f -> 521792

__device__ __forceinline__ float sigm(float v) { return 1.f / (1.f + expf(-v)); }
__device__ __forceinline__ float dis_of(float dg) {
    return dg > 0.f ? rsqrtf(fmaxf(dg, 1e-20f)) : 0.f;
}

// Scan 1: zero ctrl/deg/bitmap; collect nbr(0); warm theta+w_hh into L3.
__global__ void k_nbr(const int* __restrict__ ei, const float* __restrict__ ew,
                      const float* __restrict__ theta_x, const float* __restrict__ theta_h,
                      const float* __restrict__ w_hh, char* __restrict__ ws) {
    int*   nbrCnt = (int*)(ws + O_NBRCNT);
    int*   nbrNode= (int*)(ws + O_NBRNODE);
    float* nbrW   = (float*)(ws + O_NBRW);

    int gid = blockIdx.x * blockDim.x + threadIdx.x;
    if (gid < (O_ZERO_END - O_MCNT) / 4) ((unsigned*)(ws + O_MCNT))[gid] = 0u;

    // L3 warm: blocks 600+ stream theta_x|theta_h|w_hh (5.75 MB) into a sink.
    if (blockIdx.x >= 600) {
        const int wb = blockIdx.x - 600, NWB = 182;
        const float4* tx4 = (const float4*)theta_x;   //  98304 f4
        const float4* th4 = (const float4*)theta_h;   // 196608 f4
        const float4* wh4 = (const float4*)w_hh;      //  65536 f4
        float acc = 0.f;
        for (int idx = wb * 256 + threadIdx.x; idx < 360448; idx += NWB * 256) {
            float4 v;
            if (idx < 98304)       v = tx4[idx];
            else if (idx < 294912) v = th4[idx - 98304];
            else                   v = wh4[idx - 294912];
            acc += v.x + v.y + v.z + v.w;
        }
        asm volatile("" :: "v"(acc));
    }

    int e0 = gid * 4;
    if (e0 >= NE) return;
    int4 d4 = *(const int4*)&ei[NE + e0];
    float4 w4 = *(const float4*)&ew[e0];
    int dd[4] = {d4.x, d4.y, d4.z, d4.w};
    float wv[4] = {w4.x, w4.y, w4.z, w4.w};
    #pragma unroll
    for (int k = 0; k < 4; ++k) {
        if (dd[k] == 0 && wv[k] != 0.f) {
            int s = ei[e0 + k];
            if (s != 0) {
                int slot = atomicAdd(nbrCnt, 1);
                if (slot < NBR_CAP) { nbrNode[slot] = s; nbrW[slot] = wv[k]; }
            }
        }
    }
}

// Scan 2: match edges with d==0 or d in nbr(0); record (s,d,w); mark needed nodes.
__global__ void k_match(const int* __restrict__ ei, const float* __restrict__ ew,
                        char* __restrict__ ws) {
    const int* nbrCnt = (const int*)(ws + O_NBRCNT);
    const int* nbrNode= (const int*)(ws + O_NBRNODE);
    int*      mCnt   = (int*)(ws + O_MCNT);
    int*      mS     = (int*)(ws + O_MS);
    int*      mD     = (int*)(ws + O_MD);
    float*    mW     = (float*)(ws + O_MW);
    unsigned* bitmap = (unsigned*)(ws + O_BITMAP);

    __shared__ int sNode[NBR_CAP];
    __shared__ int sCnt;
    if (threadIdx.x == 0) sCnt = min(*nbrCnt, NBR_CAP);
    __syncthreads();
    int cnt = sCnt;
    for (int i = threadIdx.x; i < cnt; i += blockDim.x) sNode[i] = nbrNode[i];
    __syncthreads();
    if (blockIdx.x == 0 && threadIdx.x == 0) atomicOr(&bitmap[0], 1u);

    int i = blockIdx.x * blockDim.x + threadIdx.x;
    int e0 = i * 4;
    if (e0 >= NE) return;
    int4 s4 = *(const int4*)&ei[e0];
    int4 d4 = *(const int4*)&ei[NE + e0];
    float4 w4 = *(const float4*)&ew[e0];
    int ss[4] = {s4.x, s4.y, s4.z, s4.w};
    int dd[4] = {d4.x, d4.y, d4.z, d4.w};
    float wv[4] = {w4.x, w4.y, w4.z, w4.w};
    bool m[4];
    #pragma unroll
    for (int k = 0; k < 4; ++k) m[k] = (dd[k] == 0);
    for (int j = 0; j < cnt; ++j) {
        int nv = sNode[j];
        #pragma unroll
        for (int k = 0; k < 4; ++k) m[k] |= (dd[k] == nv);
    }
    #pragma unroll
    for (int k = 0; k < 4; ++k) {
        int s = ss[k], d = dd[k];
        float w = wv[k];
        if (s == d || w == 0.f || !m[k]) continue;
        int slot = atomicAdd(mCnt, 1);
        if (slot < M_CAP) { mS[slot] = s; mD[slot] = d; mW[slot] = w; }
        atomicOr(&bitmap[s >> 5], 1u << (s & 31));
        atomicOr(&bitmap[d >> 5], 1u << (d & 31));
    }
}

// Scan 3: deg[s] += w for bitmap-marked srcs; warm matched x/h rows into L3.
__global__ void k_deg(const int* __restrict__ ei, const float* __restrict__ ew,
                      const float* __restrict__ x, const float* __restrict__ h,
                      char* __restrict__ ws) {
    const unsigned* bitmap = (const unsigned*)(ws + O_BITMAP);
    const int* mCnt = (const int*)(ws + O_MCNT);
    const int* mS   = (const int*)(ws + O_MS);
    float* deg = (float*)(ws + O_DEG);

    // Row warm: blocks 700+ touch every matched src row of x and h (sunk).
    if (blockIdx.x >= 700) {
        const int wb = blockIdx.x - 700, NWB = 82;
        int cnt = min(*mCnt, M_CAP);
        float acc = 0.f;
        int tid = threadIdx.x;
        for (int i = wb; i < cnt; i += NWB) {
            int s = mS[i];
            if (tid < 32)       { float4 v = ((const float4*)(x + (size_t)s * FD))[tid];       acc += v.x; }
            else if (tid < 96)  { float4 v = ((const float4*)(h + (size_t)s * HDIM))[tid - 32]; acc += v.x; }
        }
        asm volatile("" :: "v"(acc));
    }

    int i = blockIdx.x * blockDim.x + threadIdx.x;
    int e0 = i * 4;
    if (e0 >= NE) return;
    int4 s4 = *(const int4*)&ei[e0];
    int4 d4 = *(const int4*)&ei[NE + e0];
    float4 w4 = *(const float4*)&ew[e0];
    int ss[4] = {s4.x, s4.y, s4.z, s4.w};
    int dd[4] = {d4.x, d4.y, d4.z, d4.w};
    float wv[4] = {w4.x, w4.y, w4.z, w4.w};
    #pragma unroll
    for (int k = 0; k < 4; ++k) {
        int s = ss[k];
        if (s == dd[k] || wv[k] == 0.f) continue;
        if (bitmap[s >> 5] & (1u << (s & 31)))
            atomicAdd(&deg[s], wv[k]);
    }
}

// Graph: 48 blocks x 256 threads. Block owns 24 p-rows (pure-x or pure-h),
// computes T-slice (4-deep pipelined gather) + gemv partials -> gpart (plain stores).
__global__ __launch_bounds__(TPB) void k_graph(
    const float* __restrict__ x, const float* __restrict__ h,
    const float* __restrict__ theta_x, const float* __restrict__ theta_h,
    char* __restrict__ ws) {

    const float* deg    = (const float*)(ws + O_DEG);
    const int*   nbrCnt = (const int*)(ws + O_NBRCNT);
    const int*   mCnt   = (const int*)(ws + O_MCNT);
    const int*   nbrNode= (const int*)(ws + O_NBRNODE);
    const float* nbrW   = (const float*)(ws + O_NBRW);
    const int*   mS     = (const int*)(ws + O_MS);
    const int*   mD     = (const int*)(ws + O_MD);
    const float* mW     = (const float*)(ws + O_MW);
    float*       gpart  = (float*)(ws + O_GPART);

    __shared__ int   sNode[NBR_CAP];
    __shared__ float sWl[NBR_CAP];
    __shared__ float cf1[ECHUNK], cf2[ECHUNK];
    __shared__ int   sS[ECHUNK];
    __shared__ float tp1[GRP][PSLICE], tp2[GRP][PSLICE];
    __shared__ float tslice[PSLICE];
    __shared__ int   sCnt, sMcnt;

    const int tid = threadIdx.x, bid = blockIdx.x;

    if (tid == 0) { sCnt = min(*nbrCnt, NBR_CAP); sMcnt = min(*mCnt, M_CAP); }
    __syncthreads();
    const int ncnt = sCnt, mcnt = sMcnt;
    for (int i = tid; i < ncnt; i += TPB) { sNode[i] = nbrNode[i]; sWl[i] = nbrW[i]; }
    __syncthreads();

    // block-uniform slice properties: blocks 0..15 -> x, 16..47 -> h
    const bool isx = bid < 16;
    const int qstart = bid * PSLICE - (isx ? 0 : 3 * FD);
    const float* fb0 = isx ? x : h;
    const int fstride = isx ? FD : HDIM;

    // ---- phase A: T-slice ----
    const float dis0 = dis_of(deg[0]);
    const int pl = tid % PSLICE, gr = tid / PSLICE;       // GRP full groups
    const int q = qstart + pl;
    const int korder = q / fstride;
    const int f = q % fstride;
    const float* fbase = fb0 + f;
    const float f0 = fbase[0];

    float a1 = 0.f, a2 = 0.f;
    for (int c0i = 0; c0i < mcnt; c0i += ECHUNK) {
        int clen = min(ECHUNK, mcnt - c0i);
        for (int i = tid; i < clen; i += TPB) {           // per-edge coefs
            int sI = mS[c0i + i], dI = mD[c0i + i];
            float w = mW[c0i + i];
            float disd = dis_of(deg[dI]);
            float wn = dis_of(deg[sI]) * w * disd;
            float Wd = 0.f;
            for (int j = 0; j < ncnt; ++j) Wd += (sNode[j] == dI) ? sWl[j] : 0.f;
            cf1[i] = (dI == 0) ? wn : 0.f;
            cf2[i] = wn * (dis0 * disd * Wd);
            sS[i] = sI;
        }
        __syncthreads();
        if (gr < GRP) {                                   // 4-deep pipelined gather
            int i = gr;
            for (; i + 3 * GRP < clen; i += 4 * GRP) {
                int s0 = sS[i], s1 = sS[i + GRP], s2 = sS[i + 2 * GRP], s3 = sS[i + 3 * GRP];
                float c10 = cf1[i], c11 = cf1[i + GRP], c12 = cf1[i + 2 * GRP], c13 = cf1[i + 3 * GRP];
                float c20 = cf2[i], c21 = cf2[i + GRP], c22 = cf2[i + 2 * GRP], c23 = cf2[i + 3 * GRP];
                float v0 = fbase[(size_t)s0 * fstride];
                float v1 = fbase[(size_t)s1 * fstride];
                float v2 = fbase[(size_t)s2 * fstride];
                float v3 = fbase[(size_t)s3 * fstride];
                a1 += c10 * v0 + c11 * v1 + c12 * v2 + c13 * v3;
                a2 += c20 * v0 + c21 * v1 + c22 * v2 + c23 * v3;
            }
            for (; i < clen; i += GRP) {
                float v = fbase[(size_t)sS[i] * fstride];
                a1 += cf1[i] * v;
                a2 += cf2[i] * v;
            }
        }
        __syncthreads();
    }
    if (gr < GRP) { tp1[gr][pl] = a1; tp2[gr][pl] = a2; }
    __syncthreads();
    if (tid < PSLICE) {
        float A1 = 0.f, A2 = 0.f;
        #pragma unroll
        for (int g2 = 0; g2 < GRP; ++g2) { A1 += tp1[g2][tid]; A2 += tp2[g2][tid]; }
        int ko = (qstart + tid) / fstride;
        float ff0 = fb0[(qstart + tid) % fstride];
        tslice[tid] = (ko == 0) ? ff0 : ((ko == 1) ? -A1 : 2.f * A2 - ff0);
    }
    __syncthreads();

    // ---- phase B: gemv over the block's 24 p-rows; plain stores to gpart ----
    {
        const float* tb = isx ? theta_x : theta_h;
        const size_t gs = isx ? (size_t)(3 * FD) * HDIM : (size_t)(3 * HDIM) * HDIM;
        float g0 = 0.f, g1 = 0.f, g2v = 0.f, g3 = 0.f;
        #pragma unroll 8
        for (int pp = 0; pp < PSLICE; ++pp) {
            float tv = tslice[pp];
            const float* row = tb + (size_t)(qstart + pp) * HDIM;
            g0  += tv * row[tid];
            g1  += tv * row[gs + tid];
            g2v += tv * row[2 * gs + tid];
            g3  += tv * row[3 * gs + tid];
        }
        float* gp = gpart + (size_t)bid * 1024;
        gp[0 * HDIM + tid] = g0;
        gp[1 * HDIM + tid] = g1;
        gp[2 * HDIM + tid] = g2v;
        gp[3 * HDIM + tid] = g3;
    }
}

// Gates: 1 block x 1024 threads. Reduce gpart (48 partials) -> gates -> h0,c0.
__global__ __launch_bounds__(1024) void k_gates(
    const float* __restrict__ c,
    const float* __restrict__ bias_x, const float* __restrict__ bias_h,
    const float* __restrict__ w_c, const float* __restrict__ b_gate,
    char* __restrict__ ws) {
    const float* gpart = (const float*)(ws + O_GPART);
    float* hbuf = (float*)(ws + O_HBUF);
    float* cbuf = (float*)(ws + O_CBUF);

    __shared__ float sg[4][HDIM];
    const int tid = threadIdx.x;
    const int g = tid >> 8, o = tid & 255;
    float s = 0.f;
    #pragma unroll 8
    for (int b = 0; b < GB; ++b) s += gpart[(size_t)b * 1024 + g * HDIM + o];
    sg[g][o] = s;
    __syncthreads();
    if (tid < HDIM) {
        float g0 = sg[0][tid] + bias_x[0 * HDIM + tid] + bias_h[0 * HDIM + tid];
        float g1 = sg[1][tid] + bias_x[1 * HDIM + tid] + bias_h[1 * HDIM + tid];
        float g2 = sg[2][tid] + bias_x[2 * HDIM + tid] + bias_h[2 * HDIM + tid];
        float g3 = sg[3][tid] + bias_x[3 * HDIM + tid] + bias_h[3 * HDIM + tid];
        float c0 = c[tid];
        float I  = sigm(g0 + w_c[0 * HDIM + tid] * c0 + b_gate[0 * HDIM + tid]);
        float Fg = sigm(g1 + w_c[1 * HDIM + tid] * c0 + b_gate[1 * HDIM + tid]);
        float Cn = Fg * c0 + I * tanhf(g2 + b_gate[2 * HDIM + tid]);
        float O  = sigm(g3 + w_c[2 * HDIM + tid] * Cn + b_gate[3 * HDIM + tid]);
        hbuf[tid] = O * tanhf(Cn);
        cbuf[tid] = Cn;
    }
}

// One LSTM step: pure dataflow, reads slot t, writes slot t+1.
__global__ __launch_bounds__(TPB) void k_step(
    int t, const float* __restrict__ x,
    const float* __restrict__ w_ih, const float* __restrict__ w_hh,
    const float* __restrict__ b_ih, const float* __restrict__ b_hh,
    const float* __restrict__ w_out, const float* __restrict__ b_out,
    float* __restrict__ out, char* __restrict__ ws) {

    float* hbuf = (float*)(ws + O_HBUF);
    float* cbuf = (float*)(ws + O_CBUF);

    __shared__ __align__(16) float sh[HDIM];
    __shared__ float sdot[32];
    __shared__ float swsum[4];

    const int tid = threadIdx.x, bid = blockIdx.x;
    const float* hr = hbuf + t * HDIM;

    float hv = hr[tid];
    sh[tid] = hv;
    float pw = hv * w_out[tid];
    pw += __shfl_down(pw, 32);
    pw += __shfl_down(pw, 16);
    pw += __shfl_down(pw, 8);
    pw += __shfl_down(pw, 4);
    pw += __shfl_down(pw, 2);
    pw += __shfl_down(pw, 1);
    if ((tid & 63) == 0) swsum[tid >> 6] = pw;
    __syncthreads();
    const float bo = b_out[0];
    const float sval = swsum[0] + swsum[1] + swsum[2] + swsum[3] + bo; // = out[t-1]
    const float sinp = (t == 0) ? x[FD - 1] : sval;
    if (t > 0 && bid == 0 && tid == 0) out[t - 1] = sval;

    const int rl = tid >> 3, seg = tid & 7;
    const int grow = (rl >> 3) * HDIM + bid * 8 + (rl & 7);
    const float* wrow = w_hh + (size_t)grow * HDIM + seg * 32;
    const float* shh = &sh[seg * 32];
    float acc = 0.f;
    #pragma unroll
    for (int k = 0; k < 8; ++k) {
        float4 wv = *(const float4*)&wrow[k * 4];
        float4 hv4 = *(const float4*)&shh[k * 4];
        acc += hv4.x * wv.x + hv4.y * wv.y + hv4.z * wv.z + hv4.w * wv.w;
    }
    acc += __shfl_down(acc, 4);
    acc += __shfl_down(acc, 2);
    acc += __shfl_down(acc, 1);
    if (seg == 0) sdot[rl] = acc + sinp * w_ih[grow] + b_ih[grow] + b_hh[grow];
    __syncthreads();

    if (tid < 8) {
        const int dim = bid * 8 + tid;
        float cd = cbuf[t * HDIM + dim];
        float iv = sdot[tid], fv = sdot[8 + tid], gv = sdot[16 + tid], ov = sdot[24 + tid];
        float cn = sigm(fv) * cd + sigm(iv) * tanhf(gv);
        float hn = sigm(ov) * tanhf(cn);
        hbuf[(t + 1) * HDIM + dim] = hn;
        cbuf[(t + 1) * HDIM + dim] = cn;
    }
}

// Final: out[TT-1] from hbuf slot TT.
__global__ void k_fin(const float* __restrict__ w_out, const float* __restrict__ b_out,
                      float* __restrict__ out, char* __restrict__ ws) {
    const float* hr = (const float*)(ws + O_HBUF) + TT * HDIM;
    const int tid = threadIdx.x;            // 64 lanes
    float pw = 0.f;
    #pragma unroll
    for (int j = 0; j < 4; ++j) pw += hr[tid * 4 + j] * w_out[tid * 4 + j];
    pw += __shfl_down(pw, 32);
    pw += __shfl_down(pw, 16);
    pw += __shfl_down(pw, 8);
    pw += __shfl_down(pw, 4);
    pw += __shfl_down(pw, 2);
    pw += __shfl_down(pw, 1);
    if (tid == 0) out[TT - 1] = pw + b_out[0];
}

extern "C" void kernel_launch(void* const* d_in, const int* in_sizes, int n_in,
                              void* d_out, int out_size, void* d_ws, size_t ws_size,
                              hipStream_t stream) {
    const float* x       = (const float*)d_in[0];
    const int*   ei      = (const int*)d_in[1];
    const float* ew      = (const float*)d_in[2];
    const float* h       = (const float*)d_in[3];
    const float* c       = (const float*)d_in[4];
    const float* theta_x = (const float*)d_in[5];
    const float* bias_x  = (const float*)d_in[6];
    const float* theta_h = (const float*)d_in[7];
    const float* bias_h  = (const float*)d_in[8];
    const float* w_c     = (const float*)d_in[9];
    const float* b_gate  = (const float*)d_in[10];
    const float* w_ih    = (const float*)d_in[11];
    const float* w_hh    = (const float*)d_in[12];
    const float* b_ih    = (const float*)d_in[13];
    const float* b_hh    = (const float*)d_in[14];
    const float* w_out   = (const float*)d_in[15];
    const float* b_out   = (const float*)d_in[16];
    char* ws = (char*)d_ws;
    float* out = (float*)d_out;

    hipMemsetAsync(ws, 0, 64, stream);          // nbrCnt; rest zeroed by k_nbr

    int eb4 = (NE / 4 + TPB - 1) / TPB;         // 782 blocks
    k_nbr<<<eb4, TPB, 0, stream>>>(ei, ew, theta_x, theta_h, w_hh, ws);
    k_match<<<eb4, TPB, 0, stream>>>(ei, ew, ws);
    k_deg<<<eb4, TPB, 0, stream>>>(ei, ew, x, h, ws);
    k_graph<<<GB, TPB, 0, stream>>>(x, h, theta_x, theta_h, ws);
    k_gates<<<1, 1024, 0, stream>>>(c, bias_x, bias_h, w_c, b_gate, ws);
    for (int t = 0; t < TT; ++t)
        k_step<<<SB, TPB, 0, stream>>>(t, x, w_ih, w_hh, b_ih, b_hh, w_out, b_out, out, ws);
    k_fin<<<1, 64, 0, stream>>>(w_out, b_out, out, ws);
}

// Round 13
// 58.512 us; speedup vs baseline: 1.3960x; 1.2573x over previous
//
#include <hip/hip_runtime.h>
#include <math.h>

#define NN 50000
#define FD 128
#define HDIM 256
#define NE 800000
#define NBR_CAP 512
#define M_CAP 8192
#define TT 7
#define TPB 256
#define GB 96              // k_graph blocks: 96 x 12 = 1152 p-values
#define PSLICE 12
#define GRP 21             // gather groups per block (256/12)
#define SB 32              // k_tail2 blocks
#define SPIN_CAP 50000000

// ws offsets
#define O_NBRCNT   0       // zeroed by 64-B memset node
#define O_MCNT     64
#define O_HSYNC    128     // (TT+1)*HDIM u64 = 16384 -> 16512
#define O_DEG      16512   // NN f -> 216512
#define O_BITMAP   216512  // 1568 u32 -> 222784
#define O_ZERO_END 222784  // k_nbr zeroes [64, 222784)
#define O_NBRNODE  222784  // NBR_CAP i
#define O_NBRW     224832  // NBR_CAP f
#define O_MS       226880  // M_CAP i
#define O_MD       259648  // M_CAP i
#define O_MW       292416  // M_CAP f
#define O_CF1      325184  // M_CAP f
#define O_CF2      357952  // M_CAP f
#define O_GPART    390720  // GB*1024 f -> 783936 (fully overwritten, no zero)

__device__ __forceinline__ float sigm(float v) { return 1.f / (1.f + expf(-v)); }
__device__ __forceinline__ float dis_of(float dg) {
    return dg > 0.f ? rsqrtf(fmaxf(dg, 1e-20f)) : 0.f;
}

// Scan 1: zero ctrl/hsync/deg/bitmap; collect nbr(0).
__global__ void k_nbr(const int* __restrict__ ei, const float* __restrict__ ew,
                      char* __restrict__ ws) {
    int*   nbrCnt = (int*)(ws + O_NBRCNT);
    int*   nbrNode= (int*)(ws + O_NBRNODE);
    float* nbrW   = (float*)(ws + O_NBRW);

    int gid = blockIdx.x * blockDim.x + threadIdx.x;
    if (gid < (O_ZERO_END - O_MCNT) / 4) ((unsigned*)(ws + O_MCNT))[gid] = 0u;

    int e0 = gid * 4;
    if (e0 >= NE) return;
    int4 d4 = *(const int4*)&ei[NE + e0];
    float4 w4 = *(const float4*)&ew[e0];
    int dd[4] = {d4.x, d4.y, d4.z, d4.w};
    float wv[4] = {w4.x, w4.y, w4.z, w4.w};
    #pragma unroll
    for (int k = 0; k < 4; ++k) {
        if (dd[k] == 0 && wv[k] != 0.f) {
            int s = ei[e0 + k];
            if (s != 0) {
                int slot = atomicAdd(nbrCnt, 1);
                if (slot < NBR_CAP) { nbrNode[slot] = s; nbrW[slot] = wv[k]; }
            }
        }
    }
}

// Scan 2: match edges with d==0 or d in nbr(0); record (s,d,w); mark needed nodes.
__global__ void k_match(const int* __restrict__ ei, const float* __restrict__ ew,
                        char* __restrict__ ws) {
    const int* nbrCnt = (const int*)(ws + O_NBRCNT);
    const int* nbrNode= (const int*)(ws + O_NBRNODE);
    int*      mCnt   = (int*)(ws + O_MCNT);
    int*      mS     = (int*)(ws + O_MS);
    int*      mD     = (int*)(ws + O_MD);
    float*    mW     = (float*)(ws + O_MW);
    unsigned* bitmap = (unsigned*)(ws + O_BITMAP);

    __shared__ int sNode[NBR_CAP];
    __shared__ int sCnt;
    if (threadIdx.x == 0) sCnt = min(*nbrCnt, NBR_CAP);
    __syncthreads();
    int cnt = sCnt;
    for (int i = threadIdx.x; i < cnt; i += blockDim.x) sNode[i] = nbrNode[i];
    __syncthreads();
    if (blockIdx.x == 0 && threadIdx.x == 0) atomicOr(&bitmap[0], 1u);

    int i = blockIdx.x * blockDim.x + threadIdx.x;
    int e0 = i * 4;
    if (e0 >= NE) return;
    int4 s4 = *(const int4*)&ei[e0];
    int4 d4 = *(const int4*)&ei[NE + e0];
    float4 w4 = *(const float4*)&ew[e0];
    int ss[4] = {s4.x, s4.y, s4.z, s4.w};
    int dd[4] = {d4.x, d4.y, d4.z, d4.w};
    float wv[4] = {w4.x, w4.y, w4.z, w4.w};
    bool m[4];
    #pragma unroll
    for (int k = 0; k < 4; ++k) m[k] = (dd[k] == 0);
    for (int j = 0; j < cnt; ++j) {
        int nv = sNode[j];
        #pragma unroll
        for (int k = 0; k < 4; ++k) m[k] |= (dd[k] == nv);
    }
    #pragma unroll
    for (int k = 0; k < 4; ++k) {
        int s = ss[k], d = dd[k];
        float w = wv[k];
        if (s == d || w == 0.f || !m[k]) continue;
        int slot = atomicAdd(mCnt, 1);
        if (slot < M_CAP) { mS[slot] = s; mD[slot] = d; mW[slot] = w; }
        atomicOr(&bitmap[s >> 5], 1u << (s & 31));
        atomicOr(&bitmap[d >> 5], 1u << (d & 31));
    }
}

// Scan 3: deg[s] += w only for bitmap-marked srcs.
__global__ void k_deg(const int* __restrict__ ei, const float* __restrict__ ew,
                      char* __restrict__ ws) {
    const unsigned* bitmap = (const unsigned*)(ws + O_BITMAP);
    float* deg = (float*)(ws + O_DEG);
    int i = blockIdx.x * blockDim.x + threadIdx.x;
    int e0 = i * 4;
    if (e0 >= NE) return;
    int4 s4 = *(const int4*)&ei[e0];
    int4 d4 = *(const int4*)&ei[NE + e0];
    float4 w4 = *(const float4*)&ew[e0];
    int ss[4] = {s4.x, s4.y, s4.z, s4.w};
    int dd[4] = {d4.x, d4.y, d4.z, d4.w};
    float wv[4] = {w4.x, w4.y, w4.z, w4.w};
    #pragma unroll
    for (int k = 0; k < 4; ++k) {
        int s = ss[k];
        if (s == dd[k] || wv[k] == 0.f) continue;
        if (bitmap[s >> 5] & (1u << (s & 31)))
            atomicAdd(&deg[s], wv[k]);
    }
}

// Coefs: ONE block computes cf1/cf2 for all matched edges (was redundant per block).
__global__ void k_coef(char* __restrict__ ws) {
    const float* deg    = (const float*)(ws + O_DEG);
    const int*   nbrCnt = (const int*)(ws + O_NBRCNT);
    const int*   mCnt   = (const int*)(ws + O_MCNT);
    const int*   nbrNode= (const int*)(ws + O_NBRNODE);
    const float* nbrW   = (const float*)(ws + O_NBRW);
    const int*   mS     = (const int*)(ws + O_MS);
    const int*   mD     = (const int*)(ws + O_MD);
    const float* mW     = (const float*)(ws + O_MW);
    float*       cf1    = (float*)(ws + O_CF1);
    float*       cf2    = (float*)(ws + O_CF2);

    __shared__ int sNode[NBR_CAP];
    __shared__ float sWl[NBR_CAP];
    __shared__ int sCnt, sMcnt;
    const int tid = threadIdx.x;
    if (tid == 0) { sCnt = min(*nbrCnt, NBR_CAP); sMcnt = min(*mCnt, M_CAP); }
    __syncthreads();
    const int ncnt = sCnt, mcnt = sMcnt;
    for (int i = tid; i < ncnt; i += TPB) { sNode[i] = nbrNode[i]; sWl[i] = nbrW[i]; }
    __syncthreads();
    const float dis0 = dis_of(deg[0]);
    for (int i = tid; i < mcnt; i += TPB) {
        int sI = mS[i], dI = mD[i];
        float w = mW[i];
        float disd = dis_of(deg[dI]);
        float wn = dis_of(deg[sI]) * w * disd;
        float Wd = 0.f;
        for (int j = 0; j < ncnt; ++j) Wd += (sNode[j] == dI) ? sWl[j] : 0.f;
        cf1[i] = (dI == 0) ? wn : 0.f;
        cf2[i] = wn * (dis0 * disd * Wd);
    }
}

// Graph: 96 blocks x 256 thr. Block owns 12 p-rows (pure-x or pure-h):
// 4-deep pipelined gather (21 groups, ~13 edges each) + gemv -> gpart.
__global__ __launch_bounds__(TPB) void k_graph(
    const float* __restrict__ x, const float* __restrict__ h,
    const float* __restrict__ theta_x, const float* __restrict__ theta_h,
    char* __restrict__ ws) {

    const int*   mCnt = (const int*)(ws + O_MCNT);
    const int*   mS   = (const int*)(ws + O_MS);
    const float* cf1  = (const float*)(ws + O_CF1);
    const float* cf2  = (const float*)(ws + O_CF2);
    float*       gpart= (float*)(ws + O_GPART);

    __shared__ float tp1[GRP][PSLICE], tp2[GRP][PSLICE];
    __shared__ float tslice[PSLICE];
    __shared__ int   sMcnt;

    const int tid = threadIdx.x, bid = blockIdx.x;
    if (tid == 0) sMcnt = min(*mCnt, M_CAP);
    __syncthreads();
    const int mcnt = sMcnt;

    const bool isx = bid < 32;                         // 32*12=384 x-rows, 64*12=768 h-rows
    const int qstart = bid * PSLICE - (isx ? 0 : 3 * FD);
    const float* fb0 = isx ? x : h;
    const int fstride = isx ? FD : HDIM;

    const int pl = tid % PSLICE, gr = tid / PSLICE;
    const float* fbase = fb0 + (qstart + pl) % fstride;

    float a1 = 0.f, a2 = 0.f;
    if (gr < GRP) {
        int i = gr;
        for (; i + 3 * GRP < mcnt; i += 4 * GRP) {
            int s0 = mS[i], s1 = mS[i + GRP], s2 = mS[i + 2 * GRP], s3 = mS[i + 3 * GRP];
            float c10 = cf1[i], c11 = cf1[i + GRP], c12 = cf1[i + 2 * GRP], c13 = cf1[i + 3 * GRP];
            float c20 = cf2[i], c21 = cf2[i + GRP], c22 = cf2[i + 2 * GRP], c23 = cf2[i + 3 * GRP];
            float v0 = fbase[(size_t)s0 * fstride];
            float v1 = fbase[(size_t)s1 * fstride];
            float v2 = fbase[(size_t)s2 * fstride];
            float v3 = fbase[(size_t)s3 * fstride];
            a1 += c10 * v0 + c11 * v1 + c12 * v2 + c13 * v3;
            a2 += c20 * v0 + c21 * v1 + c22 * v2 + c23 * v3;
        }
        for (; i < mcnt; i += GRP) {
            float v = fbase[(size_t)mS[i] * fstride];
            a1 += cf1[i] * v;
            a2 += cf2[i] * v;
        }
        tp1[gr][pl] = a1; tp2[gr][pl] = a2;
    }
    __syncthreads();
    if (tid < PSLICE) {
        float A1 = 0.f, A2 = 0.f;
        #pragma unroll
        for (int g2 = 0; g2 < GRP; ++g2) { A1 += tp1[g2][tid]; A2 += tp2[g2][tid]; }
        int q = qstart + tid;
        int ko = q / fstride;
        float ff0 = fb0[q % fstride];
        tslice[tid] = (ko == 0) ? ff0 : ((ko == 1) ? -A1 : 2.f * A2 - ff0);
    }
    __syncthreads();

    {   // gemv over the block's 12 p-rows; plain stores to gpart
        const float* tb = isx ? theta_x : theta_h;
        const size_t gs = isx ? (size_t)(3 * FD) * HDIM : (size_t)(3 * HDIM) * HDIM;
        float g0 = 0.f, g1 = 0.f, g2v = 0.f, g3 = 0.f;
        #pragma unroll
        for (int pp = 0; pp < PSLICE; ++pp) {
            float tv = tslice[pp];
            const float* row = tb + (size_t)(qstart + pp) * HDIM;
            g0  += tv * row[tid];
            g1  += tv * row[gs + tid];
            g2v += tv * row[2 * gs + tid];
            g3  += tv * row[3 * gs + tid];
        }
        float* gp = gpart + (size_t)bid * 1024;
        gp[tid] = g0;
        gp[HDIM + tid] = g1;
        gp[2 * HDIM + tid] = g2v;
        gp[3 * HDIM + tid] = g3;
    }
}

// Tail: 32 blocks x 256 thr. Reduce gpart for own 32 gate-dims -> gates ->
// 7 LSTM steps with tagged-u64 h exchange (r10-proven) -> out[0..6].
__global__ __launch_bounds__(TPB) void k_tail2(
    const float* __restrict__ x, const float* __restrict__ c,
    const float* __restrict__ bias_x, const float* __restrict__ bias_h,
    const float* __restrict__ w_c, const float* __restrict__ b_gate,
    const float* __restrict__ w_ih, const float* __restrict__ w_hh,
    const float* __restrict__ b_ih, const float* __restrict__ b_hh,
    const float* __restrict__ w_out, const float* __restrict__ b_out,
    float* __restrict__ out, char* __restrict__ ws) {

    unsigned long long* hsync = (unsigned long long*)(ws + O_HSYNC);
    const float* gpart = (const float*)(ws + O_GPART);

    __shared__ __align__(16) float sh[HDIM];
    __shared__ float sdot[32];
    __shared__ float swsum[4];

    const int tid = threadIdx.x, bid = blockIdx.x;

    // w_hh rows in VGPRs (r5/r6-proven no-spill layout: 32 rows/block, 8 thr/row)
    const int rl = tid >> 3, seg = tid & 7;
    const int grow = (rl >> 3) * HDIM + bid * 8 + (rl & 7);
    float4 wreg[8];
    #pragma unroll
    for (int k = 0; k < 8; ++k)
        wreg[k] = *(const float4*)&w_hh[(size_t)grow * HDIM + seg * 32 + k * 4];
    const float wih_r = w_ih[grow];
    const float br    = b_ih[grow] + b_hh[grow];
    const float bo    = b_out[0];
    const float wout_r = w_out[tid];

    // reduce gpart for this block's 32 gate-dims: d = g*8+k, 8 threads/dim
    {
        const int d = tid >> 3, j = tid & 7;
        const int g = d >> 3, kk = d & 7, o = bid * 8 + kk;
        float s = 0.f;
        #pragma unroll
        for (int pb = j; pb < GB; pb += 8) s += gpart[(size_t)pb * 1024 + g * HDIM + o];
        s += __shfl_down(s, 4);
        s += __shfl_down(s, 2);
        s += __shfl_down(s, 1);
        if (j == 0) sdot[d] = s;
    }
    __syncthreads();

    // gates for this block's 8 dims -> h0 (tagged store), c0 in creg
    float creg = 0.f;
    if (tid < 8) {
        const int o = bid * 8 + tid;
        float g0 = sdot[tid]      + bias_x[o]            + bias_h[o];
        float g1 = sdot[8 + tid]  + bias_x[HDIM + o]     + bias_h[HDIM + o];
        float g2 = sdot[16 + tid] + bias_x[2 * HDIM + o] + bias_h[2 * HDIM + o];
        float g3 = sdot[24 + tid] + bias_x[3 * HDIM + o] + bias_h[3 * HDIM + o];
        float c0 = c[o];
        float I  = sigm(g0 + w_c[o] * c0 + b_gate[o]);
        float Fg = sigm(g1 + w_c[HDIM + o] * c0 + b_gate[HDIM + o]);
        float Cn = Fg * c0 + I * tanhf(g2 + b_gate[2 * HDIM + o]);
        float O  = sigm(g3 + w_c[2 * HDIM + o] * Cn + b_gate[3 * HDIM + o]);
        float h0 = O * tanhf(Cn);
        creg = Cn;
        unsigned long long pk = (1ull << 32) | (unsigned long long)__float_as_uint(h0);
        __hip_atomic_store(&hsync[o], pk, __ATOMIC_RELAXED, __HIP_MEMORY_SCOPE_SYSTEM);
    }
    // pull full h0 (wave 0: 4 tagged words per thread)
    if (tid < 64) {
        #pragma unroll
        for (int j = 0; j < 4; ++j) {
            unsigned long long v;
            int sp = 0;
            do {
                v = __hip_atomic_load(&hsync[tid * 4 + j],
                                      __ATOMIC_RELAXED, __HIP_MEMORY_SCOPE_SYSTEM);
                if ((unsigned)(v >> 32) == 1u) break;
                __builtin_amdgcn_s_sleep(1);
            } while (++sp < SPIN_CAP);
            sh[tid * 4 + j] = __uint_as_float((unsigned)v);
        }
    }
    __syncthreads();
    float sinp = x[FD - 1];

    for (int t = 0; t < TT; ++t) {
        // dot on sh = h(t)
        float acc = 0.f;
        const float* shh = &sh[seg * 32];
        #pragma unroll
        for (int k = 0; k < 8; ++k) {
            float4 hv = *(const float4*)&shh[k * 4];
            acc += hv.x * wreg[k].x + hv.y * wreg[k].y + hv.z * wreg[k].z + hv.w * wreg[k].w;
        }
        acc += __shfl_down(acc, 4);
        acc += __shfl_down(acc, 2);
        acc += __shfl_down(acc, 1);
        if (seg == 0) sdot[rl] = acc + sinp * wih_r + br;
        __syncthreads();                        // S1: sh reads done, sdot ready
        if (tid < 8) {
            float iv = sdot[tid], fv = sdot[8 + tid], gv = sdot[16 + tid], ov = sdot[24 + tid];
            float cn = sigm(fv) * creg + sigm(iv) * tanhf(gv);
            float hn = sigm(ov) * tanhf(cn);
            creg = cn;
            unsigned long long pk = (((unsigned long long)(t + 2)) << 32)
                                  | (unsigned long long)__float_as_uint(hn);
            __hip_atomic_store(&hsync[(t + 1) * HDIM + bid * 8 + tid], pk,
                               __ATOMIC_RELAXED, __HIP_MEMORY_SCOPE_SYSTEM);
        }
        if (tid < 64) {                         // pull full h(t+1)
            #pragma unroll
            for (int j = 0; j < 4; ++j) {
                unsigned long long v;
                int sp = 0;
                do {
                    v = __hip_atomic_load(&hsync[(t + 1) * HDIM + tid * 4 + j],
                                          __ATOMIC_RELAXED, __HIP_MEMORY_SCOPE_SYSTEM);
                    if ((unsigned)(v >> 32) == (unsigned)(t + 2)) break;
                    __builtin_amdgcn_s_sleep(1);
                } while (++sp < SPIN_CAP);
                sh[tid * 4 + j] = __uint_as_float((unsigned)v);
            }
        }
        __syncthreads();                        // S2: new h visible to all
        float pw = wout_r * sh[tid];            // out[t] = w_out . h(t+1) + bo
        pw += __shfl_down(pw, 32);
        pw += __shfl_down(pw, 16);
        pw += __shfl_down(pw, 8);
        pw += __shfl_down(pw, 4);
        pw += __shfl_down(pw, 2);
        pw += __shfl_down(pw, 1);
        if ((tid & 63) == 0) swsum[tid >> 6] = pw;
        __syncthreads();                        // S3: swsum ready
        float sval = swsum[0] + swsum[1] + swsum[2] + swsum[3] + bo;
        sinp = sval;                            // input to step t+1
        if (bid == 0 && tid == 0) out[t] = sval;
    }
}

extern "C" void kernel_launch(void* const* d_in, const int* in_sizes, int n_in,
                              void* d_out, int out_size, void* d_ws, size_t ws_size,
                              hipStream_t stream) {
    const float* x       = (const float*)d_in[0];
    const int*   ei      = (const int*)d_in[1];
    const float* ew      = (const float*)d_in[2];
    const float* h       = (const float*)d_in[3];
    const float* c       = (const float*)d_in[4];
    const float* theta_x = (const float*)d_in[5];
    const float* bias_x  = (const float*)d_in[6];
    const float* theta_h = (const float*)d_in[7];
    const float* bias_h  = (const float*)d_in[8];
    const float* w_c     = (const float*)d_in[9];
    const float* b_gate  = (const float*)d_in[10];
    const float* w_ih    = (const float*)d_in[11];
    const float* w_hh    = (const float*)d_in[12];
    const float* b_ih    = (const float*)d_in[13];
    const float* b_hh    = (const float*)d_in[14];
    const float* w_out   = (const float*)d_in[15];
    const float* b_out   = (const float*)d_in[16];
    char* ws = (char*)d_ws;
    float* out = (float*)d_out;

    hipMemsetAsync(ws, 0, 64, stream);          // nbrCnt; rest zeroed by k_nbr

    int eb4 = (NE / 4 + TPB - 1) / TPB;         // 782 blocks
    k_nbr<<<eb4, TPB, 0, stream>>>(ei, ew, ws);
    k_match<<<eb4, TPB, 0, stream>>>(ei, ew, ws);
    k_deg<<<eb4, TPB, 0, stream>>>(ei, ew, ws);
    k_coef<<<1, TPB, 0, stream>>>(ws);
    k_graph<<<GB, TPB, 0, stream>>>(x, h, theta_x, theta_h, ws);
    k_tail2<<<SB, TPB, 0, stream>>>(x, c, bias_x, bias_h, w_c, b_gate,
                                    w_ih, w_hh, b_ih, b_hh, w_out, b_out, out, ws);
}

// Round 14
// 53.058 us; speedup vs baseline: 1.5395x; 1.1028x over previous
//
#include <hip/hip_runtime.h>
#include <math.h>

#define NN 50000
#define FD 128
#define HDIM 256
#define NE 800000
#define NBR_CAP 512
#define M_CAP 8192
#define TT 7
#define TPB 256
#define GB 96              // k_graph blocks: 96 x 12 = 1152 p-values
#define PSLICE 12
#define GRP 21             // gather groups per block (252 threads used)
#define ECHUNK 2048
#define SB 32              // k_tail2 blocks
#define SPIN_CAP 50000000

// ws offsets
#define O_NBRCNT   0       // zeroed by 64-B memset node
#define O_MCNT     64
#define O_HSYNC    128     // (TT+1)*HDIM u64 = 16384 -> 16512
#define O_DEG      16512   // NN f -> 216512
#define O_BITMAP   216512  // 1568 u32 -> 222784
#define O_ZERO_END 222784  // k_nbr zeroes [64, 222784)
#define O_NBRNODE  222784  // NBR_CAP i
#define O_NBRW     224832  // NBR_CAP f
#define O_MS       226880  // M_CAP i
#define O_MD       259648  // M_CAP i
#define O_MW       292416  // M_CAP f -> 325184
#define O_GPART    325184  // GB*1024 f -> 718400 (fully overwritten, no zero)

__device__ __forceinline__ float sigm(float v) { return 1.f / (1.f + expf(-v)); }
__device__ __forceinline__ float dis_of(float dg) {
    return dg > 0.f ? rsqrtf(fmaxf(dg, 1e-20f)) : 0.f;
}

// Scan 1: zero ctrl/hsync/deg/bitmap; collect nbr(0).
__global__ void k_nbr(const int* __restrict__ ei, const float* __restrict__ ew,
                      char* __restrict__ ws) {
    int*   nbrCnt = (int*)(ws + O_NBRCNT);
    int*   nbrNode= (int*)(ws + O_NBRNODE);
    float* nbrW   = (float*)(ws + O_NBRW);

    int gid = blockIdx.x * blockDim.x + threadIdx.x;
    if (gid < (O_ZERO_END - O_MCNT) / 4) ((unsigned*)(ws + O_MCNT))[gid] = 0u;

    int e0 = gid * 4;
    if (e0 >= NE) return;
    int4 d4 = *(const int4*)&ei[NE + e0];
    float4 w4 = *(const float4*)&ew[e0];
    int dd[4] = {d4.x, d4.y, d4.z, d4.w};
    float wv[4] = {w4.x, w4.y, w4.z, w4.w};
    #pragma unroll
    for (int k = 0; k < 4; ++k) {
        if (dd[k] == 0 && wv[k] != 0.f) {
            int s = ei[e0 + k];
            if (s != 0) {
                int slot = atomicAdd(nbrCnt, 1);
                if (slot < NBR_CAP) { nbrNode[slot] = s; nbrW[slot] = wv[k]; }
            }
        }
    }
}

// Scan 2: match edges with d==0 or d in nbr(0); record (s,d,w); mark needed nodes.
__global__ void k_match(const int* __restrict__ ei, const float* __restrict__ ew,
                        char* __restrict__ ws) {
    const int* nbrCnt = (const int*)(ws + O_NBRCNT);
    const int* nbrNode= (const int*)(ws + O_NBRNODE);
    int*      mCnt   = (int*)(ws + O_MCNT);
    int*      mS     = (int*)(ws + O_MS);
    int*      mD     = (int*)(ws + O_MD);
    float*    mW     = (float*)(ws + O_MW);
    unsigned* bitmap = (unsigned*)(ws + O_BITMAP);

    __shared__ int sNode[NBR_CAP];
    __shared__ int sCnt;
    if (threadIdx.x == 0) sCnt = min(*nbrCnt, NBR_CAP);
    __syncthreads();
    int cnt = sCnt;
    for (int i = threadIdx.x; i < cnt; i += blockDim.x) sNode[i] = nbrNode[i];
    __syncthreads();
    if (blockIdx.x == 0 && threadIdx.x == 0) atomicOr(&bitmap[0], 1u);

    int i = blockIdx.x * blockDim.x + threadIdx.x;
    int e0 = i * 4;
    if (e0 >= NE) return;
    int4 s4 = *(const int4*)&ei[e0];
    int4 d4 = *(const int4*)&ei[NE + e0];
    float4 w4 = *(const float4*)&ew[e0];
    int ss[4] = {s4.x, s4.y, s4.z, s4.w};
    int dd[4] = {d4.x, d4.y, d4.z, d4.w};
    float wv[4] = {w4.x, w4.y, w4.z, w4.w};
    bool m[4];
    #pragma unroll
    for (int k = 0; k < 4; ++k) m[k] = (dd[k] == 0);
    for (int j = 0; j < cnt; ++j) {
        int nv = sNode[j];
        #pragma unroll
        for (int k = 0; k < 4; ++k) m[k] |= (dd[k] == nv);
    }
    #pragma unroll
    for (int k = 0; k < 4; ++k) {
        int s = ss[k], d = dd[k];
        float w = wv[k];
        if (s == d || w == 0.f || !m[k]) continue;
        int slot = atomicAdd(mCnt, 1);
        if (slot < M_CAP) { mS[slot] = s; mD[slot] = d; mW[slot] = w; }
        atomicOr(&bitmap[s >> 5], 1u << (s & 31));
        atomicOr(&bitmap[d >> 5], 1u << (d & 31));
    }
}

// Scan 3: deg[s] += w only for bitmap-marked srcs.
__global__ void k_deg(const int* __restrict__ ei, const float* __restrict__ ew,
                      char* __restrict__ ws) {
    const unsigned* bitmap = (const unsigned*)(ws + O_BITMAP);
    float* deg = (float*)(ws + O_DEG);
    int i = blockIdx.x * blockDim.x + threadIdx.x;
    int e0 = i * 4;
    if (e0 >= NE) return;
    int4 s4 = *(const int4*)&ei[e0];
    int4 d4 = *(const int4*)&ei[NE + e0];
    float4 w4 = *(const float4*)&ew[e0];
    int ss[4] = {s4.x, s4.y, s4.z, s4.w};
    int dd[4] = {d4.x, d4.y, d4.z, d4.w};
    float wv[4] = {w4.x, w4.y, w4.z, w4.w};
    #pragma unroll
    for (int k = 0; k < 4; ++k) {
        int s = ss[k];
        if (s == dd[k] || wv[k] == 0.f) continue;
        if (bitmap[s >> 5] & (1u << (s & 31)))
            atomicAdd(&deg[s], wv[k]);
    }
}

// Graph: 96 blocks x 256 thr. Per chunk: inline coef (cheap, overlappable) ->
// 4-deep pipelined gather (21 groups, ~13 edges each). Then tslice + gemv -> gpart.
__global__ __launch_bounds__(TPB) void k_graph(
    const float* __restrict__ x, const float* __restrict__ h,
    const float* __restrict__ theta_x, const float* __restrict__ theta_h,
    char* __restrict__ ws) {

    const float* deg    = (const float*)(ws + O_DEG);
    const int*   nbrCnt = (const int*)(ws + O_NBRCNT);
    const int*   mCnt   = (const int*)(ws + O_MCNT);
    const int*   nbrNode= (const int*)(ws + O_NBRNODE);
    const float* nbrW   = (const float*)(ws + O_NBRW);
    const int*   mS     = (const int*)(ws + O_MS);
    const int*   mD     = (const int*)(ws + O_MD);
    const float* mW     = (const float*)(ws + O_MW);
    float*       gpart  = (float*)(ws + O_GPART);

    __shared__ int   sNode[NBR_CAP];
    __shared__ float sWl[NBR_CAP];
    __shared__ float cf1[ECHUNK], cf2[ECHUNK];
    __shared__ int   sS[ECHUNK];
    __shared__ float tp1[GRP][PSLICE], tp2[GRP][PSLICE];
    __shared__ float tslice[PSLICE];
    __shared__ int   sCnt, sMcnt;

    const int tid = threadIdx.x, bid = blockIdx.x;
    if (tid == 0) { sCnt = min(*nbrCnt, NBR_CAP); sMcnt = min(*mCnt, M_CAP); }
    __syncthreads();
    const int ncnt = sCnt, mcnt = sMcnt;
    for (int i = tid; i < ncnt; i += TPB) { sNode[i] = nbrNode[i]; sWl[i] = nbrW[i]; }
    __syncthreads();

    const bool isx = bid < 32;                         // 384 x-rows, 768 h-rows
    const int qstart = bid * PSLICE - (isx ? 0 : 3 * FD);
    const float* fb0 = isx ? x : h;
    const int fstride = isx ? FD : HDIM;

    const int pl = tid % PSLICE, gr = tid / PSLICE;
    const float* fbase = fb0 + (qstart + pl) % fstride;
    const float dis0 = dis_of(deg[0]);

    float a1 = 0.f, a2 = 0.f;
    for (int c0i = 0; c0i < mcnt; c0i += ECHUNK) {
        int clen = min(ECHUNK, mcnt - c0i);
        for (int i = tid; i < clen; i += TPB) {        // inline per-edge coefs
            int sI = mS[c0i + i], dI = mD[c0i + i];
            float w = mW[c0i + i];
            float disd = dis_of(deg[dI]);
            float wn = dis_of(deg[sI]) * w * disd;
            float Wd = 0.f;
            for (int j = 0; j < ncnt; ++j) Wd += (sNode[j] == dI) ? sWl[j] : 0.f;
            cf1[i] = (dI == 0) ? wn : 0.f;
            cf2[i] = wn * (dis0 * disd * Wd);
            sS[i] = sI;
        }
        __syncthreads();
        if (gr < GRP) {                                // 4-deep pipelined gather
            int i = gr;
            for (; i + 3 * GRP < clen; i += 4 * GRP) {
                int s0 = sS[i], s1 = sS[i + GRP], s2 = sS[i + 2 * GRP], s3 = sS[i + 3 * GRP];
                float c10 = cf1[i], c11 = cf1[i + GRP], c12 = cf1[i + 2 * GRP], c13 = cf1[i + 3 * GRP];
                float c20 = cf2[i], c21 = cf2[i + GRP], c22 = cf2[i + 2 * GRP], c23 = cf2[i + 3 * GRP];
                float v0 = fbase[(size_t)s0 * fstride];
                float v1 = fbase[(size_t)s1 * fstride];
                float v2 = fbase[(size_t)s2 * fstride];
                float v3 = fbase[(size_t)s3 * fstride];
                a1 += c10 * v0 + c11 * v1 + c12 * v2 + c13 * v3;
                a2 += c20 * v0 + c21 * v1 + c22 * v2 + c23 * v3;
            }
            for (; i < clen; i += GRP) {
                float v = fbase[(size_t)sS[i] * fstride];
                a1 += cf1[i] * v;
                a2 += cf2[i] * v;
            }
        }
        __syncthreads();
    }
    if (gr < GRP) { tp1[gr][pl] = a1; tp2[gr][pl] = a2; }
    __syncthreads();
    if (tid < PSLICE) {
        float A1 = 0.f, A2 = 0.f;
        #pragma unroll
        for (int g2 = 0; g2 < GRP; ++g2) { A1 += tp1[g2][tid]; A2 += tp2[g2][tid]; }
        int q = qstart + tid;
        int ko = q / fstride;
        float ff0 = fb0[q % fstride];
        tslice[tid] = (ko == 0) ? ff0 : ((ko == 1) ? -A1 : 2.f * A2 - ff0);
    }
    __syncthreads();

    {   // gemv over the block's 12 p-rows; plain stores to gpart
        const float* tb = isx ? theta_x : theta_h;
        const size_t gs = isx ? (size_t)(3 * FD) * HDIM : (size_t)(3 * HDIM) * HDIM;
        float g0 = 0.f, g1 = 0.f, g2v = 0.f, g3 = 0.f;
        #pragma unroll
        for (int pp = 0; pp < PSLICE; ++pp) {
            float tv = tslice[pp];
            const float* row = tb + (size_t)(qstart + pp) * HDIM;
            g0  += tv * row[tid];
            g1  += tv * row[gs + tid];
            g2v += tv * row[2 * gs + tid];
            g3  += tv * row[3 * gs + tid];
        }
        float* gp = gpart + (size_t)bid * 1024;
        gp[tid] = g0;
        gp[HDIM + tid] = g1;
        gp[2 * HDIM + tid] = g2v;
        gp[3 * HDIM + tid] = g3;
    }
}

// Tail: 32 blocks x 256 thr. gpart reduce -> gates -> 7 steps. Exchange rounds:
// producers (tid<8) store tagged u64; ALL 256 threads busy-poll their own word
// in parallel and keep the payload in a register for the w_out reduce.
__global__ __launch_bounds__(TPB) void k_tail2(
    const float* __restrict__ x, const float* __restrict__ c,
    const float* __restrict__ bias_x, const float* __restrict__ bias_h,
    const float* __restrict__ w_c, const float* __restrict__ b_gate,
    const float* __restrict__ w_ih, const float* __restrict__ w_hh,
    const float* __restrict__ b_ih, const float* __restrict__ b_hh,
    const float* __restrict__ w_out, const float* __restrict__ b_out,
    float* __restrict__ out, char* __restrict__ ws) {

    unsigned long long* hsync = (unsigned long long*)(ws + O_HSYNC);
    const float* gpart = (const float*)(ws + O_GPART);

    __shared__ __align__(16) float sh[HDIM];
    __shared__ float sdot[32];
    __shared__ float swsum[4];

    const int tid = threadIdx.x, bid = blockIdx.x;

    // w_hh rows in VGPRs (proven no-spill layout: 32 rows/block, 8 thr/row)
    const int rl = tid >> 3, seg = tid & 7;
    const int grow = (rl >> 3) * HDIM + bid * 8 + (rl & 7);
    float4 wreg[8];
    #pragma unroll
    for (int k = 0; k < 8; ++k)
        wreg[k] = *(const float4*)&w_hh[(size_t)grow * HDIM + seg * 32 + k * 4];
    const float wih_r = w_ih[grow];
    const float br    = b_ih[grow] + b_hh[grow];
    const float bo    = b_out[0];
    const float wout_r = w_out[tid];

    // gpart reduce for this block's 32 gate-dims: d = tid>>3, 8 threads/dim
    {
        const int d = tid >> 3, j = tid & 7;
        const int g = d >> 3, kk = d & 7, o = bid * 8 + kk;
        float s = 0.f;
        #pragma unroll
        for (int pb = j; pb < GB; pb += 8) s += gpart[(size_t)pb * 1024 + g * HDIM + o];
        s += __shfl_down(s, 4);
        s += __shfl_down(s, 2);
        s += __shfl_down(s, 1);
        if (j == 0) sdot[d] = s;
    }
    __syncthreads();

    // gates -> h0 store (tag 1); c0 in creg
    float creg = 0.f;
    if (tid < 8) {
        const int o = bid * 8 + tid;
        float g0 = sdot[tid]      + bias_x[o]            + bias_h[o];
        float g1 = sdot[8 + tid]  + bias_x[HDIM + o]     + bias_h[HDIM + o];
        float g2 = sdot[16 + tid] + bias_x[2 * HDIM + o] + bias_h[2 * HDIM + o];
        float g3 = sdot[24 + tid] + bias_x[3 * HDIM + o] + bias_h[3 * HDIM + o];
        float c0 = c[o];
        float I  = sigm(g0 + w_c[o] * c0 + b_gate[o]);
        float Fg = sigm(g1 + w_c[HDIM + o] * c0 + b_gate[HDIM + o]);
        float Cn = Fg * c0 + I * tanhf(g2 + b_gate[2 * HDIM + o]);
        float O  = sigm(g3 + w_c[2 * HDIM + o] * Cn + b_gate[3 * HDIM + o]);
        float h0 = O * tanhf(Cn);
        creg = Cn;
        unsigned long long pk = (1ull << 32) | (unsigned long long)__float_as_uint(h0);
        __hip_atomic_store(&hsync[o], pk, __ATOMIC_RELAXED, __HIP_MEMORY_SCOPE_SYSTEM);
    }
    // parallel poll: every thread its own h0 word (busy-spin, no sleep)
    {
        unsigned long long v;
        int sp = 0;
        do {
            v = __hip_atomic_load(&hsync[tid], __ATOMIC_RELAXED, __HIP_MEMORY_SCOPE_SYSTEM);
            if ((unsigned)(v >> 32) == 1u) break;
        } while (++sp < SPIN_CAP);
        sh[tid] = __uint_as_float((unsigned)v);
    }
    __syncthreads();
    float sinp = x[FD - 1];

    for (int t = 0; t < TT; ++t) {
        // dot on sh = h(t)
        float acc = 0.f;
        const float* shh = &sh[seg * 32];
        #pragma unroll
        for (int k = 0; k < 8; ++k) {
            float4 hv = *(const float4*)&shh[k * 4];
            acc += hv.x * wreg[k].x + hv.y * wreg[k].y + hv.z * wreg[k].z + hv.w * wreg[k].w;
        }
        acc += __shfl_down(acc, 4);
        acc += __shfl_down(acc, 2);
        acc += __shfl_down(acc, 1);
        if (seg == 0) sdot[rl] = acc + sinp * wih_r + br;
        __syncthreads();                        // S1: sh reads done, sdot ready
        if (tid < 8) {
            float iv = sdot[tid], fv = sdot[8 + tid], gv = sdot[16 + tid], ov = sdot[24 + tid];
            float cn = sigm(fv) * creg + sigm(iv) * tanhf(gv);
            float hn = sigm(ov) * tanhf(cn);
            creg = cn;
            unsigned long long pk = (((unsigned long long)(t + 2)) << 32)
                                  | (unsigned long long)__float_as_uint(hn);
            __hip_atomic_store(&hsync[(t + 1) * HDIM + bid * 8 + tid], pk,
                               __ATOMIC_RELAXED, __HIP_MEMORY_SCOPE_SYSTEM);
        }
        // parallel poll: every thread its own h(t+1) word; payload stays in reg
        float hval;
        {
            unsigned long long v;
            int sp = 0;
            do {
                v = __hip_atomic_load(&hsync[(t + 1) * HDIM + tid],
                                      __ATOMIC_RELAXED, __HIP_MEMORY_SCOPE_SYSTEM);
                if ((unsigned)(v >> 32) == (unsigned)(t + 2)) break;
            } while (++sp < SPIN_CAP);
            hval = __uint_as_float((unsigned)v);
        }
        sh[tid] = hval;
        float pw = wout_r * hval;               // register payload, no LDS wait
        pw += __shfl_down(pw, 32);
        pw += __shfl_down(pw, 16);
        pw += __shfl_down(pw, 8);
        pw += __shfl_down(pw, 4);
        pw += __shfl_down(pw, 2);
        pw += __shfl_down(pw, 1);
        if ((tid & 63) == 0) swsum[tid >> 6] = pw;
        __syncthreads();                        // S2: swsum + new sh visible
        float sval = swsum[0] + swsum[1] + swsum[2] + swsum[3] + bo;
        sinp = sval;                            // input to step t+1
        if (bid == 0 && tid == 0) out[t] = sval;
    }
}

extern "C" void kernel_launch(void* const* d_in, const int* in_sizes, int n_in,
                              void* d_out, int out_size, void* d_ws, size_t ws_size,
                              hipStream_t stream) {
    const float* x       = (const float*)d_in[0];
    const int*   ei      = (const int*)d_in[1];
    const float* ew      = (const float*)d_in[2];
    const float* h       = (const float*)d_in[3];
    const float* c       = (const float*)d_in[4];
    const float* theta_x = (const float*)d_in[5];
    const float* bias_x  = (const float*)d_in[6];
    const float* theta_h = (const float*)d_in[7];
    const float* bias_h  = (const float*)d_in[8];
    const float* w_c     = (const float*)d_in[9];
    const float* b_gate  = (const float*)d_in[10];
    const float* w_ih    = (const float*)d_in[11];
    const float* w_hh    = (const float*)d_in[12];
    const float* b_ih    = (const float*)d_in[13];
    const float* b_hh    = (const float*)d_in[14];
    const float* w_out   = (const float*)d_in[15];
    const float* b_out   = (const float*)d_in[16];
    char* ws = (char*)d_ws;
    float* out = (float*)d_out;

    hipMemsetAsync(ws, 0, 64, stream);          // nbrCnt; rest zeroed by k_nbr

    int eb4 = (NE / 4 + TPB - 1) / TPB;         // 782 blocks
    k_nbr<<<eb4, TPB, 0, stream>>>(ei, ew, ws);
    k_match<<<eb4, TPB, 0, stream>>>(ei, ew, ws);
    k_deg<<<eb4, TPB, 0, stream>>>(ei, ew, ws);
    k_graph<<<GB, TPB, 0, stream>>>(x, h, theta_x, theta_h, ws);
    k_tail2<<<SB, TPB, 0, stream>>>(x, c, bias_x, bias_h, w_c, b_gate,
                                    w_ih, w_hh, b_ih, b_hh, w_out, b_out, out, ws);
}